// Round 5
// baseline (870.901 us; speedup 1.0000x reference)
//
#include <hip/hip_runtime.h>
#include <math.h>

typedef __attribute__((ext_vector_type(8))) _Float16 half8;
typedef __attribute__((ext_vector_type(4))) float f32x4;
typedef __attribute__((ext_vector_type(4))) unsigned int u32x4;

namespace {
constexpr int NS   = 32000;
constexpr int PAD  = 200;
constexpr int NT   = 201;     // frames
constexpr int TOUT = 192;
constexpr int AUD_ELEMS = 33536;          // fp16 audio region (u16 elems)
constexpr int PW_STRIDE = 232;            // power row stride (u16)
constexpr int PW_ROWS   = 208;
constexpr int PW_OFF    = AUD_ELEMS;
constexpr int BAS_KS = 13, BAS_NT = 28;   // DFT basis: K=416, N=448 (cols 0..401 live)
constexpr int FB_KS  = 7,  FB_NT  = 8;    // mel fb: K=224, N=128
constexpr int BAS_ELEMS = BAS_KS * BAS_NT * 64 * 8;   // 186368
constexpr int FB_ELEMS  = FB_KS  * FB_NT  * 64 * 8;   // 28672
constexpr int LDS_BYTES = (AUD_ELEMS + PW_ROWS * PW_STRIDE) * 2;  // 163584 <= 163840
}

// audio-LDS XOR swizzle: breaks the 320B frame-stride bank conflict.
__device__ __forceinline__ int swz(int e) { return e ^ (((e >> 7) & 3) << 3); }

__global__ void setup_tables(unsigned short* __restrict__ ws) {
  int idx = blockIdx.x * 256 + threadIdx.x;
  if (idx < BAS_ELEMS) {
    int j = idx & 7, lane = (idx >> 3) & 63, rest = idx >> 9;
    int nt = rest % BAS_NT, ks = rest / BAS_NT;
    int k   = ks * 32 + ((lane >> 4) << 3) + j;
    int col = nt * 16 + (lane & 15);
    float v = 0.f;
    if (k < 400 && col < 402) {
      int bin = col >> 1;
      int mm  = (k * bin) % 400;
      float th = (float)mm * 0.015707963267948967f;    // 2*pi/400
      float tr = (col & 1) ? sinf(th) : cosf(th);
      float wn = 0.5f * (1.0f - cosf((float)k * 0.015707963267948967f));
      v = wn * tr;
    }
    _Float16 h = (_Float16)v;
    ws[idx] = __builtin_bit_cast(unsigned short, h);
  } else if (idx < BAS_ELEMS + FB_ELEMS) {
    int i2 = idx - BAS_ELEMS;
    int j = i2 & 7, lane = (i2 >> 3) & 63, rest = i2 >> 9;
    int nt = rest % FB_NT, ks = rest / FB_NT;
    int k   = ks * 32 + ((lane >> 4) << 3) + j;        // freq bin
    int mel = nt * 16 + (lane & 15);
    float v = 0.f;
    if (k <= 200) {
      double mhi = 2595.0 * log10(1.0 + 8000.0 / 700.0);
      double ml = mhi * (double)mel / 129.0;
      double mc = mhi * (double)(mel + 1) / 129.0;
      double mr = mhi * (double)(mel + 2) / 129.0;
      double fl = 700.0 * (pow(10.0, ml / 2595.0) - 1.0);
      double fc = 700.0 * (pow(10.0, mc / 2595.0) - 1.0);
      double fr = 700.0 * (pow(10.0, mr / 2595.0) - 1.0);
      double f  = 40.0 * (double)k;
      double wv = fmin((f - fl) / (fc - fl), (fr - f) / (fr - fc));
      v = (float)fmax(0.0, wv);
    }
    _Float16 h = (_Float16)v;
    ws[idx] = __builtin_bit_cast(unsigned short, h);
  }
}

__global__ __launch_bounds__(512) __attribute__((amdgpu_waves_per_eu(2, 2)))
void melpcen_main(const float* __restrict__ audio, const unsigned short* __restrict__ ws,
                  float* __restrict__ out)
{
  extern __shared__ unsigned char ldsraw[];
  unsigned short* au   = (unsigned short*)ldsraw;           // fp16 audio (swizzled)
  unsigned short* pw16 = (unsigned short*)ldsraw + PW_OFF;  // fp16 power [208][232]
  float*          melp = (float*)ldsraw;                    // P5+: mel/pcen fp32 [201][128]
  const int tid = threadIdx.x;
  const int b   = blockIdx.x;
  const float* __restrict__ ab = audio + (size_t)b * NS;

  // ---- phase 1: zero power region; audio -> LDS fp16 (reflect pad, swizzled) ----
  for (int i = tid; i < PW_ROWS * PW_STRIDE; i += 512) pw16[i] = 0;
  for (int i = tid; i < AUD_ELEMS; i += 512) {
    float v = 0.f;
    if (i < NS + 2 * PAD) {
      int pos = i - PAD;
      if (pos < 0) pos = -pos;
      if (pos >= NS) pos = 2 * NS - 2 - pos;
      v = ab[pos];
    }
    _Float16 h = (_Float16)v;
    au[swz(i)] = __builtin_bit_cast(unsigned short, h);
  }
  __syncthreads();

  const int w = tid >> 6, lane = tid & 63;
  const int lr = lane & 15, lg = lane >> 4;
  const int mhalf = w >> 2, ngrp = w & 3;   // mt = mhalf*6 + mm (tile 6 duplicated)

  // ---- phase 2: DFT via fp16 MFMA. C[frame][col], cols interleaved cos/sin ----
  f32x4 acc[7][7];
  #pragma unroll
  for (int mm = 0; mm < 7; ++mm)
    #pragma unroll
    for (int n = 0; n < 7; ++n) acc[mm][n] = (f32x4){0.f, 0.f, 0.f, 0.f};
  {
    const int laneA = lr * 160 + lg * 8;
    const int mbase = mhalf * 6;
    for (int ks = 0; ks < 13; ++ks) {
      half8 Bf[7];
      const unsigned short* bsrc = ws + ((size_t)((ks * 28 + ngrp * 7) * 64 + lane)) * 8;
      #pragma unroll
      for (int n = 0; n < 7; ++n) {
        Bf[n] = *(const half8*)(bsrc + n * 512);
        u32x4 t = __builtin_bit_cast(u32x4, Bf[n]);
        asm volatile("" : "+v"(t));                  // pin: forbid remat/reload
        Bf[n] = __builtin_bit_cast(half8, t);
      }
      #pragma unroll
      for (int mm = 0; mm < 7; ++mm) {
        int e = (mbase + mm) * 2560 + ks * 32 + laneA;
        half8 Af = *(const half8*)(au + swz(e));
        #pragma unroll
        for (int n = 0; n < 7; ++n)
          acc[mm][n] = __builtin_amdgcn_mfma_f32_16x16x32_f16(Af, Bf[n], acc[mm][n], 0, 0, 0);
      }
    }
  }
  __syncthreads();   // audio reads done

  // ---- phase 3: power = re^2+im^2 -> fp16 LDS [row][bin], stride 232 ----
  #pragma unroll
  for (int mm = 0; mm < 7; ++mm) {
    int mt = mhalf * 6 + mm;
    #pragma unroll
    for (int n = 0; n < 7; ++n) {
      int gcol = (ngrp * 7 + n) * 16 + lr;
      #pragma unroll
      for (int j = 0; j < 4; ++j) {
        float v = acc[mm][n][j];
        float q = __shfl_xor(v, 1);            // partner col (re<->im)
        int row = mt * 16 + lg * 4 + j;
        if (!(gcol & 1) && gcol < 402 && row < NT) {
          _Float16 h = (_Float16)fmaf(v, v, q * q);
          pw16[row * PW_STRIDE + (gcol >> 1)] = __builtin_bit_cast(unsigned short, h);
        }
      }
    }
  }
  __syncthreads();

  // ---- phase 4: mel = power x fb via fp16 MFMA (fp32 accum); hold in regs ----
  float melv[13][4];
  {
    half8 Fb[7];
    const unsigned short* fsrc = ws + BAS_ELEMS + (size_t)w * 512 + (size_t)lane * 8;
    #pragma unroll
    for (int ks = 0; ks < 7; ++ks) Fb[ks] = *(const half8*)(fsrc + ks * 4096);
    for (int mt = 0; mt < 13; ++mt) {
      f32x4 a2 = (f32x4){0.f, 0.f, 0.f, 0.f};
      const unsigned short* psrc = pw16 + (mt * 16 + lr) * PW_STRIDE + lg * 8;
      #pragma unroll
      for (int ks = 0; ks < 7; ++ks)
        a2 = __builtin_amdgcn_mfma_f32_16x16x32_f16(*(const half8*)(psrc + ks * 32), Fb[ks], a2, 0, 0, 0);
      #pragma unroll
      for (int j = 0; j < 4; ++j) melv[mt][j] = a2[j];
    }
  }
  __syncthreads();   // power reads done; LDS free for fp32 mel
  {
    const int melcol = w * 16 + lr;
    #pragma unroll
    for (int mt = 0; mt < 13; ++mt) {
      #pragma unroll
      for (int j = 0; j < 4; ++j) {
        int row = mt * 16 + lg * 4 + j;
        if (row < NT) melp[row * 128 + melcol] = melv[mt][j];
      }
    }
  }
  __syncthreads();

  // ---- phase 5: PCEN fp32, 4-chunk parallel linear scan, in-place ----
  const int m = tid & 127, c = tid >> 7;
  {
    const int t0  = (c == 0) ? 0 : (51 + 50 * (c - 1));
    const int len = (c == 0) ? 51 : 50;
    float M = 0.f;
    for (int t = t0; t < t0 + len; ++t) {
      float e = melp[t * 128 + m];
      M = (t == 0) ? e : fmaf(0.96f, M, 0.04f * e);
    }
    float* carry = melp + 25728;   // [4][128] fp32
    float* minb  = melp + 26240;   // [4][128] fp32
    carry[c * 128 + m] = M;
    __syncthreads();
    if (c == 0) {
      float a50 = exp2f(50.0f * log2f(0.96f));   // 0.96^50
      float m1 = carry[m];
      float m2 = fmaf(a50, m1, carry[128 + m]);
      float m3 = fmaf(a50, m2, carry[256 + m]);
      minb[128 + m] = m1; minb[256 + m] = m2; minb[384 + m] = m3;
    }
    __syncthreads();
    float Min = (c == 0) ? 0.f : minb[c * 128 + m];
    float wf = 1.f, Mloc = 0.f;
    for (int t = t0; t < t0 + len; ++t) {
      float e = melp[t * 128 + m];
      Mloc = (t == 0) ? e : fmaf(0.96f, Mloc, 0.04f * e);
      wf *= 0.96f;
      float Mt = fmaf(wf, Min, Mloc);
      float dn = exp2f(0.8f * log2f(1e-8f + Mt));     // (1e-8+M)^0.8
      float pc = sqrtf(e / dn + 2.0f) - 1.41421356237309515f;
      melp[t * 128 + m] = pc;
    }
  }
  __syncthreads();

  // ---- phase 6: antialiased linear resize 201 -> 192 (time), fp32 store ----
  {
    float* __restrict__ ob = out + (size_t)b * (TOUT * 128);
    const float INVS = 201.0f / 192.0f;
    for (int i = c; i < TOUT; i += 4) {
      float ct = ((float)i + 0.5f) * INVS - 0.5f;
      int jlo = (int)ceilf(ct - INVS);
      int jhi = (int)floorf(ct + INVS);
      if (jlo < 0) jlo = 0;
      if (jhi > NT - 1) jhi = NT - 1;
      float wsum = 0.f, val = 0.f;
      for (int j = jlo; j <= jhi; ++j) {
        float wv = 1.0f - fabsf((float)j - ct) / INVS;
        if (wv > 0.f) { wsum += wv; val = fmaf(wv, melp[j * 128 + m], val); }
      }
      ob[(size_t)i * 128 + m] = val / wsum;
    }
  }
}

extern "C" void kernel_launch(void* const* d_in, const int* in_sizes, int n_in,
                              void* d_out, int out_size, void* d_ws, size_t ws_size,
                              hipStream_t stream) {
  (void)in_sizes; (void)n_in; (void)out_size; (void)ws_size;
  unsigned short* ws = (unsigned short*)d_ws;
  setup_tables<<<(BAS_ELEMS + FB_ELEMS + 255) / 256, 256, 0, stream>>>(ws);
  melpcen_main<<<2048, 512, LDS_BYTES, stream>>>((const float*)d_in[0], ws, (float*)d_out);
}

// Round 6
// 672.724 us; speedup vs baseline: 1.2946x; 1.2946x over previous
//
#include <hip/hip_runtime.h>
#include <math.h>

typedef __attribute__((ext_vector_type(8))) _Float16 half8;
typedef __attribute__((ext_vector_type(4))) float f32x4;
typedef __attribute__((ext_vector_type(4))) unsigned int u32x4;

namespace {
constexpr int NS = 32000, PAD = 200, NT = 201, TOUT = 192, NMEL = 128;
constexpr int FRB = 48, NSTRIP = 5;            // 48-frame strips, 5*48=240 >= 201
constexpr int AU_SPAN = 8192;                  // staged u16 elems (need 47*160+400=7920)
constexpr int PW_STRIDE = 232, PW_ROWS = 48;   // fp16 power strip
constexpr int BAS_NT = 28;                     // DFT basis: K=416 (13x32), N=448
constexpr int BAS_ELEMS = 13 * 28 * 64 * 8;    // 186368 u16
constexpr int FB_ELEMS  = 7 * 8 * 64 * 8;      // 28672 u16
constexpr int OUT_ROW_U16 = TOUT * NMEL * 2;   // 49152 u16 per out row (98304 B)
constexpr int MEL_OFF_U16 = OUT_ROW_U16 - NT * NMEL;  // 23424 (mel fp16 in row's tail)
}

// audio-LDS XOR swizzle: breaks the 320B frame-stride bank conflict (elem bits[4:3] ^= bits[8:7])
__device__ __forceinline__ int swz(int e) { return e ^ (((e >> 7) & 3) << 3); }
__device__ __forceinline__ unsigned short f2h(float f) {
  _Float16 h = (_Float16)f; return __builtin_bit_cast(unsigned short, h);
}
__device__ __forceinline__ float h2f(unsigned short u) {
  return (float)__builtin_bit_cast(_Float16, u);
}

// ws tables, fp16, MFMA fragment layout (proven R4/R5):
//  [0, BAS_ELEMS): DFT basis frag[ks][nt][lane][j]: k=ks*32+(lane>>4)*8+j, col=nt*16+(lane&15)
//                  col even -> win[k]*cos(2*pi*bin*k/400), odd -> sin; bin=col/2
//  [BAS_ELEMS, +FB_ELEMS): mel fb frag[ks][nt][lane][j]: k=freq bin, col=mel
__global__ void setup_tables(unsigned short* __restrict__ ws) {
  int idx = blockIdx.x * 256 + threadIdx.x;
  if (idx < BAS_ELEMS) {
    int j = idx & 7, lane = (idx >> 3) & 63, rest = idx >> 9;
    int nt = rest % BAS_NT, ks = rest / BAS_NT;
    int k   = ks * 32 + ((lane >> 4) << 3) + j;
    int col = nt * 16 + (lane & 15);
    float v = 0.f;
    if (k < 400 && col < 402) {
      int bin = col >> 1;
      int mm  = (k * bin) % 400;
      float th = (float)mm * 0.015707963267948967f;   // 2*pi/400
      float tr = (col & 1) ? sinf(th) : cosf(th);
      float wn = 0.5f * (1.0f - cosf((float)k * 0.015707963267948967f));
      v = wn * tr;
    }
    ws[idx] = f2h(v);
  } else if (idx < BAS_ELEMS + FB_ELEMS) {
    int i2 = idx - BAS_ELEMS;
    int j = i2 & 7, lane = (i2 >> 3) & 63, rest = i2 >> 9;
    int nt = rest % 8, ks = rest / 8;
    int k   = ks * 32 + ((lane >> 4) << 3) + j;       // freq bin
    int mel = nt * 16 + (lane & 15);
    float v = 0.f;
    if (k <= 200) {
      double mhi = 2595.0 * log10(1.0 + 8000.0 / 700.0);
      double ml = mhi * (double)mel / 129.0;
      double mc = mhi * (double)(mel + 1) / 129.0;
      double mr = mhi * (double)(mel + 2) / 129.0;
      double fl = 700.0 * (pow(10.0, ml / 2595.0) - 1.0);
      double fc = 700.0 * (pow(10.0, mc / 2595.0) - 1.0);
      double fr = 700.0 * (pow(10.0, mr / 2595.0) - 1.0);
      double f  = 40.0 * (double)k;
      double wv = fmin((f - fl) / (fc - fl), (fr - f) / (fr - fc));
      v = (float)fmax(0.0, wv);
    }
    ws[idx] = f2h(v);
  }
}

// ---- Kernel A: per 48-frame strip: DFT (MFMA) -> power -> mel (MFMA) -> packed fp16 in d_out ----
__global__ __launch_bounds__(256) __attribute__((amdgpu_waves_per_eu(4)))
void dft_mel_kernel(const float* __restrict__ audio, const unsigned short* __restrict__ ws,
                    unsigned short* __restrict__ outu)
{
  __shared__ unsigned short au[AU_SPAN];              // 16 KB
  __shared__ unsigned short pw16[PW_ROWS * PW_STRIDE];// 22.3 KB
  const int tid = threadIdx.x;
  const int bid = blockIdx.x;
  const int r = bid / NSTRIP, s = bid % NSTRIP;
  const int t0 = s * FRB;
  const float* __restrict__ ab = audio + (size_t)r * NS;
  const int g0 = t0 * 160 - PAD;

  // phase 1: stage audio strip fp16 (reflect pad), zero power pad cols 201..231
  for (int i = tid; i < AU_SPAN; i += 256) {
    int g = g0 + i;
    if (g < 0) g = -g;
    if (g >= NS) g = 2 * NS - 2 - g;
    au[swz(i)] = f2h(ab[g]);
  }
  for (int i = tid; i < PW_ROWS * 32; i += 256) {
    int row = i >> 5, sl = i & 31;
    if (sl) pw16[row * PW_STRIDE + 200 + sl] = 0;
  }
  __syncthreads();

  const int w = tid >> 6, lane = tid & 63, lr = lane & 15, lg = lane >> 4;

  // phase 2: DFT. C[local frame][col], cols interleaved cos/sin. acc[3][7] = 84 VGPR.
  f32x4 acc[3][7];
  #pragma unroll
  for (int mm = 0; mm < 3; ++mm)
    #pragma unroll
    for (int n = 0; n < 7; ++n) acc[mm][n] = (f32x4){0.f, 0.f, 0.f, 0.f};
  {
    const int laneA = lr * 160 + lg * 8;
    for (int ks = 0; ks < 13; ++ks) {
      half8 Af[3];
      #pragma unroll
      for (int mm = 0; mm < 3; ++mm)
        Af[mm] = *(const half8*)(au + swz(mm * 2560 + ks * 32 + laneA));
      const unsigned short* bsrc = ws + ((size_t)((ks * BAS_NT + w * 7) * 64 + lane)) * 8;
      #pragma unroll
      for (int n = 0; n < 7; ++n) {
        half8 Bf = *(const half8*)(bsrc + n * 512);
        #pragma unroll
        for (int mm = 0; mm < 3; ++mm)
          acc[mm][n] = __builtin_amdgcn_mfma_f32_16x16x32_f16(Af[mm], Bf, acc[mm][n], 0, 0, 0);
      }
    }
  }

  // phase 3: power = re^2 + im^2 -> fp16 LDS strip
  #pragma unroll
  for (int mm = 0; mm < 3; ++mm) {
    #pragma unroll
    for (int n = 0; n < 7; ++n) {
      int gcol = (w * 7 + n) * 16 + lr;
      #pragma unroll
      for (int j = 0; j < 4; ++j) {
        float v = acc[mm][n][j];
        float q = __shfl_xor(v, 1);             // partner col (re<->im)
        int row = mm * 16 + lg * 4 + j;
        if (!(gcol & 1) && gcol < 402)
          pw16[row * PW_STRIDE + (gcol >> 1)] = f2h(fmaf(v, v, q * q));
      }
    }
  }
  __syncthreads();

  // phase 4: mel = power x fb (MFMA, fp32 accum); pack fp16 into d_out row tail
  #pragma unroll
  for (int mt = 0; mt < 3; ++mt) {
    #pragma unroll
    for (int nt = 0; nt < 2; ++nt) {
      f32x4 a2 = (f32x4){0.f, 0.f, 0.f, 0.f};
      const unsigned short* psrc = pw16 + (mt * 16 + lr) * PW_STRIDE + lg * 8;
      const unsigned short* fsrc = ws + BAS_ELEMS + ((size_t)(2 * w + nt) * 64 + lane) * 8;
      #pragma unroll
      for (int ks = 0; ks < 7; ++ks)
        a2 = __builtin_amdgcn_mfma_f32_16x16x32_f16(*(const half8*)(psrc + ks * 32),
                                                    *(const half8*)(fsrc + (size_t)ks * 4096),
                                                    a2, 0, 0, 0);
      int gm = (2 * w + nt) * 16 + lr;
      #pragma unroll
      for (int j = 0; j < 4; ++j) {
        int t = t0 + mt * 16 + lg * 4 + j;
        if (t < NT)
          outu[(size_t)r * OUT_ROW_U16 + MEL_OFF_U16 + t * NMEL + gm] = f2h(a2[j]);
      }
    }
  }
}

// ---- Kernel B: per row: mel -> LDS, PCEN serial scan + streaming antialiased resize ----
__global__ __launch_bounds__(128)
void pcen_resize_kernel(unsigned short* __restrict__ outu)
{
  __shared__ u32x4 melv[(NT * NMEL) / 8];   // 51456 B, fp16 mel row
  unsigned short* mel = (unsigned short*)melv;
  const int m = threadIdx.x;
  const int r = blockIdx.x;
  const unsigned short* src = outu + (size_t)r * OUT_ROW_U16 + MEL_OFF_U16;
  for (int i = m; i < (NT * NMEL) / 8; i += 128)
    melv[i] = *(const u32x4*)(src + (size_t)i * 8);
  __syncthreads();

  float* __restrict__ ob = (float*)outu + (size_t)r * TOUT * NMEL;
  float M = 0.f, p0 = 0.f, p1 = 0.f, p2 = 0.f;
  int next_i = 0;
  const float INVS = 201.0f / 192.0f, R = INVS;
  for (int t = 0; t < NT; ++t) {
    float e = h2f(mel[t * NMEL + m]);
    M = (t == 0) ? e : fmaf(0.96f, M, 0.04f * e);
    float dn = exp2f(0.8f * log2f(1e-8f + M));        // (1e-8+M)^0.8
    float pc = sqrtf(e / dn + 2.0f) - 1.41421356237309515f;
    p2 = p1; p1 = p0; p0 = pc;
    while (next_i < TOUT) {
      float ct = ((float)next_i + 0.5f) * INVS - 0.5f;
      int jhi = (int)floorf(ct + R);
      if (jhi > NT - 1) jhi = NT - 1;
      if (jhi != t) break;
      int jlo = (int)ceilf(ct - R);
      if (jlo < 0) jlo = 0;
      float wsum = 0.f, val = 0.f;
      #pragma unroll 3
      for (int j = jlo; j <= jhi; ++j) {
        float wv = 1.0f - fabsf((float)j - ct) / R;
        wv = fmaxf(wv, 0.0f);
        wsum += wv;
        int d = t - j;
        float pv = (d == 0) ? p0 : ((d == 1) ? p1 : p2);
        val = fmaf(wv, pv, val);
      }
      ob[(size_t)next_i * NMEL + m] = val / wsum;
      ++next_i;
    }
  }
}

extern "C" void kernel_launch(void* const* d_in, const int* in_sizes, int n_in,
                              void* d_out, int out_size, void* d_ws, size_t ws_size,
                              hipStream_t stream) {
  (void)in_sizes; (void)n_in; (void)out_size; (void)ws_size;
  unsigned short* ws = (unsigned short*)d_ws;
  setup_tables<<<(BAS_ELEMS + FB_ELEMS + 255) / 256, 256, 0, stream>>>(ws);
  dft_mel_kernel<<<2048 * NSTRIP, 256, 0, stream>>>((const float*)d_in[0], ws,
                                                    (unsigned short*)d_out);
  pcen_resize_kernel<<<2048, 128, 0, stream>>>((unsigned short*)d_out);
}

// Round 7
// 475.269 us; speedup vs baseline: 1.8324x; 1.4155x over previous
//
#include <hip/hip_runtime.h>
#include <math.h>

typedef __attribute__((ext_vector_type(8))) _Float16 half8;
typedef __attribute__((ext_vector_type(4))) float f32x4;
typedef __attribute__((ext_vector_type(4))) unsigned int u32x4;

namespace {
constexpr int NS = 32000, PAD = 200, NT = 201, TOUT = 192, NMEL = 128;
constexpr int FRB = 48, NSTRIP = 5;            // 48-frame strips, 5*48=240 >= 201
constexpr int AU_SPAN = 8192;                  // staged u16 elems (need 47*160+400=7920)
constexpr int PW_STRIDE = 232, PW_ROWS = 48;   // fp16 power strip
constexpr int BAS_NT = 28;                     // DFT basis: K=416 (13x32), N=448
constexpr int BAS_ELEMS = 13 * 28 * 64 * 8;    // 186368 u16
constexpr int FB_ELEMS  = 7 * 8 * 64 * 8;      // 28672 u16
constexpr int OUT_ROW_U16 = TOUT * NMEL * 2;   // 49152 u16 per out row (98304 B)
constexpr int MEL_OFF_U16 = OUT_ROW_U16 - NT * NMEL;  // 23424 (mel fp16 in row's tail)
}

// audio-LDS XOR swizzle: breaks the 320B frame-stride bank conflict (elem bits[4:3] ^= bits[8:7])
__device__ __forceinline__ int swz(int e) { return e ^ (((e >> 7) & 3) << 3); }
__device__ __forceinline__ unsigned short f2h(float f) {
  _Float16 h = (_Float16)f; return __builtin_bit_cast(unsigned short, h);
}
__device__ __forceinline__ float h2f(unsigned short u) {
  return (float)__builtin_bit_cast(_Float16, u);
}

// ws tables, fp16, MFMA fragment layout (proven R4-R6):
//  [0, BAS_ELEMS): DFT basis frag[ks][nt][lane][j]: k=ks*32+(lane>>4)*8+j, col=nt*16+(lane&15)
//                  col even -> win[k]*cos(2*pi*bin*k/400), odd -> sin; bin=col/2
//  [BAS_ELEMS, +FB_ELEMS): mel fb frag[ks][nt][lane][j]: k=freq bin, col=mel
__global__ void setup_tables(unsigned short* __restrict__ ws) {
  int idx = blockIdx.x * 256 + threadIdx.x;
  if (idx < BAS_ELEMS) {
    int j = idx & 7, lane = (idx >> 3) & 63, rest = idx >> 9;
    int nt = rest % BAS_NT, ks = rest / BAS_NT;
    int k   = ks * 32 + ((lane >> 4) << 3) + j;
    int col = nt * 16 + (lane & 15);
    float v = 0.f;
    if (k < 400 && col < 402) {
      int bin = col >> 1;
      int mm  = (k * bin) % 400;
      float th = (float)mm * 0.015707963267948967f;   // 2*pi/400
      float tr = (col & 1) ? sinf(th) : cosf(th);
      float wn = 0.5f * (1.0f - cosf((float)k * 0.015707963267948967f));
      v = wn * tr;
    }
    ws[idx] = f2h(v);
  } else if (idx < BAS_ELEMS + FB_ELEMS) {
    int i2 = idx - BAS_ELEMS;
    int j = i2 & 7, lane = (i2 >> 3) & 63, rest = i2 >> 9;
    int nt = rest % 8, ks = rest / 8;
    int k   = ks * 32 + ((lane >> 4) << 3) + j;       // freq bin
    int mel = nt * 16 + (lane & 15);
    float v = 0.f;
    if (k <= 200) {
      double mhi = 2595.0 * log10(1.0 + 8000.0 / 700.0);
      double ml = mhi * (double)mel / 129.0;
      double mc = mhi * (double)(mel + 1) / 129.0;
      double mr = mhi * (double)(mel + 2) / 129.0;
      double fl = 700.0 * (pow(10.0, ml / 2595.0) - 1.0);
      double fc = 700.0 * (pow(10.0, mc / 2595.0) - 1.0);
      double fr = 700.0 * (pow(10.0, mr / 2595.0) - 1.0);
      double f  = 40.0 * (double)k;
      double wv = fmin((f - fl) / (fc - fl), (fr - f) / (fr - fc));
      v = (float)fmax(0.0, wv);
    }
    ws[idx] = f2h(v);
  }
}

// ---- Kernel A: per 48-frame strip: DFT (MFMA) -> power -> mel (MFMA) -> packed fp16 in d_out ----
__global__ __launch_bounds__(256) __attribute__((amdgpu_waves_per_eu(4)))
void dft_mel_kernel(const float* __restrict__ audio, const unsigned short* __restrict__ ws,
                    unsigned short* __restrict__ outu)
{
  __shared__ unsigned short au[AU_SPAN];              // 16 KB
  __shared__ unsigned short pw16[PW_ROWS * PW_STRIDE];// 22.3 KB
  const int tid = threadIdx.x;
  const int bid = blockIdx.x;
  const int r = bid / NSTRIP, s = bid % NSTRIP;
  const int t0 = s * FRB;
  const float* __restrict__ ab = audio + (size_t)r * NS;
  const int g0 = t0 * 160 - PAD;

  // phase 1: stage audio strip fp16 (reflect pad), zero power pad cols 201..231
  for (int i = tid; i < AU_SPAN; i += 256) {
    int g = g0 + i;
    if (g < 0) g = -g;
    if (g >= NS) g = 2 * NS - 2 - g;
    au[swz(i)] = f2h(ab[g]);
  }
  for (int i = tid; i < PW_ROWS * 32; i += 256) {
    int row = i >> 5, sl = i & 31;
    if (sl) pw16[row * PW_STRIDE + 200 + sl] = 0;
  }
  __syncthreads();

  const int w = tid >> 6, lane = tid & 63, lr = lane & 15, lg = lane >> 4;

  // phase 2: DFT. C[local frame][col], cols interleaved cos/sin. acc[3][7] = 84 VGPR.
  f32x4 acc[3][7];
  #pragma unroll
  for (int mm = 0; mm < 3; ++mm)
    #pragma unroll
    for (int n = 0; n < 7; ++n) acc[mm][n] = (f32x4){0.f, 0.f, 0.f, 0.f};
  {
    const int laneA = lr * 160 + lg * 8;
    for (int ks = 0; ks < 13; ++ks) {
      half8 Af[3];
      #pragma unroll
      for (int mm = 0; mm < 3; ++mm)
        Af[mm] = *(const half8*)(au + swz(mm * 2560 + ks * 32 + laneA));
      const unsigned short* bsrc = ws + ((size_t)((ks * BAS_NT + w * 7) * 64 + lane)) * 8;
      #pragma unroll
      for (int n = 0; n < 7; ++n) {
        half8 Bf = *(const half8*)(bsrc + n * 512);
        #pragma unroll
        for (int mm = 0; mm < 3; ++mm)
          acc[mm][n] = __builtin_amdgcn_mfma_f32_16x16x32_f16(Af[mm], Bf, acc[mm][n], 0, 0, 0);
      }
    }
  }

  // phase 3: power = re^2 + im^2 -> fp16 LDS strip
  #pragma unroll
  for (int mm = 0; mm < 3; ++mm) {
    #pragma unroll
    for (int n = 0; n < 7; ++n) {
      int gcol = (w * 7 + n) * 16 + lr;
      #pragma unroll
      for (int j = 0; j < 4; ++j) {
        float v = acc[mm][n][j];
        float q = __shfl_xor(v, 1);             // partner col (re<->im)
        int row = mm * 16 + lg * 4 + j;
        if (!(gcol & 1) && gcol < 402)
          pw16[row * PW_STRIDE + (gcol >> 1)] = f2h(fmaf(v, v, q * q));
      }
    }
  }
  __syncthreads();

  // phase 4: mel = power x fb (MFMA, fp32 accum); pack fp16 into d_out row tail
  #pragma unroll
  for (int mt = 0; mt < 3; ++mt) {
    #pragma unroll
    for (int nt = 0; nt < 2; ++nt) {
      f32x4 a2 = (f32x4){0.f, 0.f, 0.f, 0.f};
      const unsigned short* psrc = pw16 + (mt * 16 + lr) * PW_STRIDE + lg * 8;
      const unsigned short* fsrc = ws + BAS_ELEMS + ((size_t)(2 * w + nt) * 64 + lane) * 8;
      #pragma unroll
      for (int ks = 0; ks < 7; ++ks)
        a2 = __builtin_amdgcn_mfma_f32_16x16x32_f16(*(const half8*)(psrc + ks * 32),
                                                    *(const half8*)(fsrc + (size_t)ks * 4096),
                                                    a2, 0, 0, 0);
      int gm = (2 * w + nt) * 16 + lr;
      #pragma unroll
      for (int j = 0; j < 4; ++j) {
        int t = t0 + mt * 16 + lg * 4 + j;
        if (t < NT)
          outu[(size_t)r * OUT_ROW_U16 + MEL_OFF_U16 + t * NMEL + gm] = f2h(a2[j]);
      }
    }
  }
}

// ---- Kernel B: per row: mel -> LDS, 4-chunk parallel PCEN scan + parallel resize ----
__global__ __launch_bounds__(512)
void pcen_resize_kernel(unsigned short* __restrict__ outu)
{
  __shared__ unsigned short mel[NT * NMEL];  // 51456 B (pcen fp16 in-place after scan)
  __shared__ float carry[4][NMEL];
  __shared__ float minb[4][NMEL];
  const int tid = threadIdx.x;
  const int r = blockIdx.x;
  const unsigned short* src = outu + (size_t)r * OUT_ROW_U16 + MEL_OFF_U16;
  for (int i = tid; i < (NT * NMEL) / 8; i += 512)
    *(u32x4*)(mel + i * 8) = *(const u32x4*)(src + (size_t)i * 8);
  __syncthreads();

  const int m = tid & 127, c = tid >> 7;
  const int t0  = (c == 0) ? 0 : (51 + 50 * (c - 1));
  const int len = (c == 0) ? 51 : 50;

  // pass 1: chunk-local EMA endpoint
  float M = 0.f;
  for (int t = t0; t < t0 + len; ++t) {
    float e = h2f(mel[t * NMEL + m]);
    M = (t == 0) ? e : fmaf(0.96f, M, 0.04f * e);
  }
  carry[c][m] = M;
  __syncthreads();
  if (c == 0) {
    float a50 = exp2f(50.0f * log2f(0.96f));   // 0.96^50
    float m1 = carry[0][m];
    float m2 = fmaf(a50, m1, carry[1][m]);
    float m3 = fmaf(a50, m2, carry[2][m]);
    minb[1][m] = m1; minb[2][m] = m2; minb[3][m] = m3;
  }
  __syncthreads();

  // pass 2: recompute with incoming prefix, write pcen fp16 in-place
  float Min = (c == 0) ? 0.f : minb[c][m];
  float wf = 1.f, Mloc = 0.f;
  for (int t = t0; t < t0 + len; ++t) {
    float e = h2f(mel[t * NMEL + m]);
    Mloc = (t == 0) ? e : fmaf(0.96f, Mloc, 0.04f * e);
    wf *= 0.96f;
    float Mt = fmaf(wf, Min, Mloc);
    float dn = exp2f(0.8f * log2f(1e-8f + Mt));     // (1e-8+M)^0.8
    float pc = sqrtf(e / dn + 2.0f) - 1.41421356237309515f;
    mel[t * NMEL + m] = f2h(pc);                    // own cell, read above
  }
  __syncthreads();

  // resize 201 -> 192 (time axis), antialiased triangle, 4-way t-parallel
  float* __restrict__ ob = (float*)outu + (size_t)r * TOUT * NMEL;
  const float INVS = 201.0f / 192.0f;
  for (int i = c; i < TOUT; i += 4) {
    float ct = ((float)i + 0.5f) * INVS - 0.5f;
    int jlo = (int)ceilf(ct - INVS);
    int jhi = (int)floorf(ct + INVS);
    if (jlo < 0) jlo = 0;
    if (jhi > NT - 1) jhi = NT - 1;
    float wsum = 0.f, val = 0.f;
    for (int j = jlo; j <= jhi; ++j) {
      float wv = 1.0f - fabsf((float)j - ct) / INVS;
      if (wv > 0.f) { wsum += wv; val = fmaf(wv, h2f(mel[j * NMEL + m]), val); }
    }
    ob[(size_t)i * NMEL + m] = val / wsum;
  }
}

extern "C" void kernel_launch(void* const* d_in, const int* in_sizes, int n_in,
                              void* d_out, int out_size, void* d_ws, size_t ws_size,
                              hipStream_t stream) {
  (void)in_sizes; (void)n_in; (void)out_size; (void)ws_size;
  unsigned short* ws = (unsigned short*)d_ws;
  setup_tables<<<(BAS_ELEMS + FB_ELEMS + 255) / 256, 256, 0, stream>>>(ws);
  dft_mel_kernel<<<2048 * NSTRIP, 256, 0, stream>>>((const float*)d_in[0], ws,
                                                    (unsigned short*)d_out);
  pcen_resize_kernel<<<2048, 512, 0, stream>>>((unsigned short*)d_out);
}

// Round 8
// 458.854 us; speedup vs baseline: 1.8980x; 1.0358x over previous
//
#include <hip/hip_runtime.h>
#include <math.h>

typedef __attribute__((ext_vector_type(8))) _Float16 half8;
typedef __attribute__((ext_vector_type(4))) float f32x4;
typedef __attribute__((ext_vector_type(4))) unsigned int u32x4;

namespace {
constexpr int NS = 32000, PAD = 200, NT = 201, TOUT = 192, NMEL = 128;
constexpr int FRB = 48, NSTRIP = 5;            // 48-frame strips, 5*48=240 >= 201
constexpr int AU_SPAN = 7936;                  // staged u16 elems (need 47*160+400=7920)
constexpr int PW_STRIDE = 232, PW_ROWS = 48;   // fp16 power strip
constexpr int BAS_NT = 28;                     // DFT basis: K=416 (13x32), N=448
constexpr int BAS_ELEMS = 13 * 28 * 64 * 8;    // 186368 u16
constexpr int FB_ELEMS  = 7 * 8 * 64 * 8;      // 28672 u16
constexpr int OUT_ROW_U16 = TOUT * NMEL * 2;   // 49152 u16 per out row (98304 B)
constexpr int MEL_OFF_U16 = OUT_ROW_U16 - NT * NMEL;  // 23424 (mel fp16 in row's tail)
}

// audio-LDS XOR swizzle: breaks the 320B frame-stride bank conflict (elem bits[4:3] ^= bits[8:7]);
// 8-elem aligned blocks stay contiguous -> b128 read/write safe.
__device__ __forceinline__ int swz(int e) { return e ^ (((e >> 7) & 3) << 3); }
__device__ __forceinline__ unsigned short f2h(float f) {
  _Float16 h = (_Float16)f; return __builtin_bit_cast(unsigned short, h);
}
__device__ __forceinline__ float h2f(unsigned short u) {
  return (float)__builtin_bit_cast(_Float16, u);
}

// ws tables, fp16, MFMA fragment layout (proven R4-R7):
//  [0, BAS_ELEMS): DFT basis frag[ks][nt][lane][j]: k=ks*32+(lane>>4)*8+j, col=nt*16+(lane&15)
//                  col even -> win[k]*cos(2*pi*bin*k/400), odd -> sin; bin=col/2
//  [BAS_ELEMS, +FB_ELEMS): mel fb frag[ks][nt][lane][j]: k=freq bin, col=mel
__global__ void setup_tables(unsigned short* __restrict__ ws) {
  int idx = blockIdx.x * 256 + threadIdx.x;
  if (idx < BAS_ELEMS) {
    int j = idx & 7, lane = (idx >> 3) & 63, rest = idx >> 9;
    int nt = rest % BAS_NT, ks = rest / BAS_NT;
    int k   = ks * 32 + ((lane >> 4) << 3) + j;
    int col = nt * 16 + (lane & 15);
    float v = 0.f;
    if (k < 400 && col < 402) {
      int bin = col >> 1;
      int mm  = (k * bin) % 400;
      float th = (float)mm * 0.015707963267948967f;   // 2*pi/400
      float tr = (col & 1) ? sinf(th) : cosf(th);
      float wn = 0.5f * (1.0f - cosf((float)k * 0.015707963267948967f));
      v = wn * tr;
    }
    ws[idx] = f2h(v);
  } else if (idx < BAS_ELEMS + FB_ELEMS) {
    int i2 = idx - BAS_ELEMS;
    int j = i2 & 7, lane = (i2 >> 3) & 63, rest = i2 >> 9;
    int nt = rest % 8, ks = rest / 8;
    int k   = ks * 32 + ((lane >> 4) << 3) + j;       // freq bin
    int mel = nt * 16 + (lane & 15);
    float v = 0.f;
    if (k <= 200) {
      double mhi = 2595.0 * log10(1.0 + 8000.0 / 700.0);
      double ml = mhi * (double)mel / 129.0;
      double mc = mhi * (double)(mel + 1) / 129.0;
      double mr = mhi * (double)(mel + 2) / 129.0;
      double fl = 700.0 * (pow(10.0, ml / 2595.0) - 1.0);
      double fc = 700.0 * (pow(10.0, mc / 2595.0) - 1.0);
      double fr = 700.0 * (pow(10.0, mr / 2595.0) - 1.0);
      double f  = 40.0 * (double)k;
      double wv = fmin((f - fl) / (fc - fl), (fr - f) / (fr - fc));
      v = (float)fmax(0.0, wv);
    }
    ws[idx] = f2h(v);
  }
}

// ---- Kernel A: per 48-frame strip: DFT (MFMA) -> power -> mel (MFMA) -> packed fp16 in d_out ----
__global__ __launch_bounds__(256) __attribute__((amdgpu_waves_per_eu(4)))
void dft_mel_kernel(const float* __restrict__ audio, const unsigned short* __restrict__ ws,
                    unsigned short* __restrict__ outu)
{
  __shared__ unsigned short au[AU_SPAN];              // 15.5 KB
  __shared__ unsigned short pw16[PW_ROWS * PW_STRIDE];// 21.8 KB
  const int tid = threadIdx.x;
  const int bid = blockIdx.x;
  const int r = bid / NSTRIP, s = bid % NSTRIP;
  const int t0 = s * FRB;
  const float* __restrict__ ab = audio + (size_t)r * NS;
  const int g0 = t0 * 160 - PAD;

  // phase 1: stage audio strip fp16, vectorized (2x float4 -> half8 -> ds_write_b128).
  // Strip 4 stages only its live 1792 elems (frames <= 200) and zero-fills the rest.
  {
    const int nchunk = AU_SPAN / 8;                       // 992
    const int live   = (s == NSTRIP - 1) ? 224 : nchunk;  // live 8-elem chunks
    #pragma unroll 4
    for (int ci = tid; ci < nchunk; ci += 256) {
      half8 hv;
      if (ci >= live) {
        hv = (half8){0, 0, 0, 0, 0, 0, 0, 0};
      } else {
        int gbase = g0 + ci * 8;
        if (gbase >= 0 && gbase + 7 < NS) {               // fast path: aligned vector loads
          const float4* p = (const float4*)(ab + gbase);
          float4 x0 = p[0], x1 = p[1];
          hv[0] = (_Float16)x0.x; hv[1] = (_Float16)x0.y;
          hv[2] = (_Float16)x0.z; hv[3] = (_Float16)x0.w;
          hv[4] = (_Float16)x1.x; hv[5] = (_Float16)x1.y;
          hv[6] = (_Float16)x1.z; hv[7] = (_Float16)x1.w;
        } else {                                          // reflect edges, scalar
          #pragma unroll
          for (int j = 0; j < 8; ++j) {
            int g = gbase + j;
            if (g < 0) g = -g;
            if (g >= NS) g = 2 * NS - 2 - g;
            hv[j] = (_Float16)ab[g];
          }
        }
      }
      *(half8*)(au + swz(ci * 8)) = hv;
    }
  }
  // zero power pad cols 201..231
  for (int i = tid; i < PW_ROWS * 32; i += 256) {
    int row = i >> 5, sl = i & 31;
    if (sl) pw16[row * PW_STRIDE + 200 + sl] = 0;
  }
  __syncthreads();

  const int w = tid >> 6, lane = tid & 63, lr = lane & 15, lg = lane >> 4;

  // phase 2: DFT. C[local frame][col], cols interleaved cos/sin. acc[3][7].
  f32x4 acc[3][7];
  #pragma unroll
  for (int mm = 0; mm < 3; ++mm)
    #pragma unroll
    for (int n = 0; n < 7; ++n) acc[mm][n] = (f32x4){0.f, 0.f, 0.f, 0.f};
  {
    const int laneA = lr * 160 + lg * 8;
    for (int ks = 0; ks < 13; ++ks) {
      half8 Af[3];
      #pragma unroll
      for (int mm = 0; mm < 3; ++mm)
        Af[mm] = *(const half8*)(au + swz(mm * 2560 + ks * 32 + laneA));
      const unsigned short* bsrc = ws + ((size_t)((ks * BAS_NT + w * 7) * 64 + lane)) * 8;
      #pragma unroll
      for (int n = 0; n < 7; ++n) {
        half8 Bf = *(const half8*)(bsrc + n * 512);
        #pragma unroll
        for (int mm = 0; mm < 3; ++mm)
          acc[mm][n] = __builtin_amdgcn_mfma_f32_16x16x32_f16(Af[mm], Bf, acc[mm][n], 0, 0, 0);
      }
    }
  }

  // phase 3: power = re^2 + im^2 -> fp16 LDS strip
  #pragma unroll
  for (int mm = 0; mm < 3; ++mm) {
    #pragma unroll
    for (int n = 0; n < 7; ++n) {
      int gcol = (w * 7 + n) * 16 + lr;
      #pragma unroll
      for (int j = 0; j < 4; ++j) {
        float v = acc[mm][n][j];
        float q = __shfl_xor(v, 1);             // partner col (re<->im)
        int row = mm * 16 + lg * 4 + j;
        if (!(gcol & 1) && gcol < 402)
          pw16[row * PW_STRIDE + (gcol >> 1)] = f2h(fmaf(v, v, q * q));
      }
    }
  }
  __syncthreads();

  // phase 4: mel = power x fb (MFMA, fp32 accum); pack fp16 into d_out row tail
  #pragma unroll
  for (int mt = 0; mt < 3; ++mt) {
    #pragma unroll
    for (int nt = 0; nt < 2; ++nt) {
      f32x4 a2 = (f32x4){0.f, 0.f, 0.f, 0.f};
      const unsigned short* psrc = pw16 + (mt * 16 + lr) * PW_STRIDE + lg * 8;
      const unsigned short* fsrc = ws + BAS_ELEMS + ((size_t)(2 * w + nt) * 64 + lane) * 8;
      #pragma unroll
      for (int ks = 0; ks < 7; ++ks)
        a2 = __builtin_amdgcn_mfma_f32_16x16x32_f16(*(const half8*)(psrc + ks * 32),
                                                    *(const half8*)(fsrc + (size_t)ks * 4096),
                                                    a2, 0, 0, 0);
      int gm = (2 * w + nt) * 16 + lr;
      #pragma unroll
      for (int j = 0; j < 4; ++j) {
        int t = t0 + mt * 16 + lg * 4 + j;
        if (t < NT)
          outu[(size_t)r * OUT_ROW_U16 + MEL_OFF_U16 + t * NMEL + gm] = f2h(a2[j]);
      }
    }
  }
}

// ---- Kernel B: per row: mel -> LDS, 4-chunk parallel PCEN scan + parallel resize ----
__global__ __launch_bounds__(512)
void pcen_resize_kernel(unsigned short* __restrict__ outu)
{
  __shared__ unsigned short mel[NT * NMEL];  // 51456 B (pcen fp16 in-place after scan)
  __shared__ float carry[4][NMEL];
  __shared__ float minb[4][NMEL];
  const int tid = threadIdx.x;
  const int r = blockIdx.x;
  const unsigned short* src = outu + (size_t)r * OUT_ROW_U16 + MEL_OFF_U16;
  for (int i = tid; i < (NT * NMEL) / 8; i += 512)
    *(u32x4*)(mel + i * 8) = *(const u32x4*)(src + (size_t)i * 8);
  __syncthreads();

  const int m = tid & 127, c = tid >> 7;
  const int t0  = (c == 0) ? 0 : (51 + 50 * (c - 1));
  const int len = (c == 0) ? 51 : 50;

  // pass 1: chunk-local EMA endpoint
  float M = 0.f;
  for (int t = t0; t < t0 + len; ++t) {
    float e = h2f(mel[t * NMEL + m]);
    M = (t == 0) ? e : fmaf(0.96f, M, 0.04f * e);
  }
  carry[c][m] = M;
  __syncthreads();
  if (c == 0) {
    float a50 = exp2f(50.0f * log2f(0.96f));   // 0.96^50
    float m1 = carry[0][m];
    float m2 = fmaf(a50, m1, carry[1][m]);
    float m3 = fmaf(a50, m2, carry[2][m]);
    minb[1][m] = m1; minb[2][m] = m2; minb[3][m] = m3;
  }
  __syncthreads();

  // pass 2: recompute with incoming prefix, write pcen fp16 in-place
  float Min = (c == 0) ? 0.f : minb[c][m];
  float wf = 1.f, Mloc = 0.f;
  for (int t = t0; t < t0 + len; ++t) {
    float e = h2f(mel[t * NMEL + m]);
    Mloc = (t == 0) ? e : fmaf(0.96f, Mloc, 0.04f * e);
    wf *= 0.96f;
    float Mt = fmaf(wf, Min, Mloc);
    float dn = exp2f(0.8f * log2f(1e-8f + Mt));     // (1e-8+M)^0.8
    float pc = sqrtf(e / dn + 2.0f) - 1.41421356237309515f;
    mel[t * NMEL + m] = f2h(pc);                    // own cell, read above
  }
  __syncthreads();

  // resize 201 -> 192 (time axis), antialiased triangle, 4-way t-parallel
  float* __restrict__ ob = (float*)outu + (size_t)r * TOUT * NMEL;
  const float INVS = 201.0f / 192.0f;
  for (int i = c; i < TOUT; i += 4) {
    float ct = ((float)i + 0.5f) * INVS - 0.5f;
    int jlo = (int)ceilf(ct - INVS);
    int jhi = (int)floorf(ct + INVS);
    if (jlo < 0) jlo = 0;
    if (jhi > NT - 1) jhi = NT - 1;
    float wsum = 0.f, val = 0.f;
    for (int j = jlo; j <= jhi; ++j) {
      float wv = 1.0f - fabsf((float)j - ct) / INVS;
      if (wv > 0.f) { wsum += wv; val = fmaf(wv, h2f(mel[j * NMEL + m]), val); }
    }
    ob[(size_t)i * NMEL + m] = val / wsum;
  }
}

extern "C" void kernel_launch(void* const* d_in, const int* in_sizes, int n_in,
                              void* d_out, int out_size, void* d_ws, size_t ws_size,
                              hipStream_t stream) {
  (void)in_sizes; (void)n_in; (void)out_size; (void)ws_size;
  unsigned short* ws = (unsigned short*)d_ws;
  setup_tables<<<(BAS_ELEMS + FB_ELEMS + 255) / 256, 256, 0, stream>>>(ws);
  dft_mel_kernel<<<2048 * NSTRIP, 256, 0, stream>>>((const float*)d_in[0], ws,
                                                    (unsigned short*)d_out);
  pcen_resize_kernel<<<2048, 512, 0, stream>>>((unsigned short*)d_out);
}